// Round 6
// baseline (406.316 us; speedup 1.0000x reference)
//
#include <hip/hip_runtime.h>

#define NN 50000
#define FDIM 256
#define HDIM 256
#define BN_EPS 1e-5f
#define RB 32     // rows per fallback GEMM block
#define KC 16
#define NP 264    // padded LDS row stride (bf16 elems)
#define SCAN_CHUNK 1024
#define NBLK_SCAN ((NN + SCAN_CHUNK - 1) / SCAN_CHUNK)

// partition params
#define BKT 32                 // nodes per bucket == fused GEMM tile rows
#define NBKT 1563              // ceil(NN/32)
#define ECAP 1280              // LDS pair capacity (mean 1024, sigma ~32 -> 8 sigma)
#define PFB 64                 // fill blocks -> ~16-pair (64B) runs per (block,bucket)
#define PSC_NPT 7              // 7*256 = 1792 >= NBKT

typedef __attribute__((ext_vector_type(8))) short short8v;
typedef __attribute__((ext_vector_type(8))) unsigned short ushort8v;
typedef __attribute__((ext_vector_type(4))) float f32x4;

__device__ __forceinline__ float b2f(unsigned short u) {
    return __uint_as_float(((unsigned)u) << 16);
}
__device__ __forceinline__ unsigned short f2b(float f) {  // RNE
    unsigned u = __float_as_uint(f);
    return (unsigned short)((u + 0x7FFFu + ((u >> 16) & 1u)) >> 16);
}

// ================= fp32 -> bf16 convert (x and W in one launch) =================
__global__ void k_cvt2(const float4* __restrict__ x, const float4* __restrict__ W,
                       ushort4* __restrict__ xb, ushort4* __restrict__ Wb,
                       int nx4, int nw4) {
    int i = blockIdx.x * blockDim.x + threadIdx.x;
    if (i < nx4) {
        float4 v = x[i];
        xb[i] = make_ushort4(f2b(v.x), f2b(v.y), f2b(v.z), f2b(v.w));
    } else {
        int j = i - nx4;
        if (j < nw4) {
            float4 v = W[j];
            Wb[j] = make_ushort4(f2b(v.x), f2b(v.y), f2b(v.z), f2b(v.w));
        }
    }
}

// ================= bucket partition (counting sort by dst>>5) =================
__launch_bounds__(256)
__global__ void k_phist(const int* __restrict__ dst, int* __restrict__ bcnt, int E) {
    __shared__ int lhist[NBKT];
    int t = threadIdx.x;
    int chunk = (E + 255) / 256;       // grid = 256 blocks
    int c0 = blockIdx.x * chunk;
    int c1 = min(E, c0 + chunk);
    for (int i = t; i < NBKT; i += 256) lhist[i] = 0;
    __syncthreads();
    for (int e = c0 + t; e < c1; e += 256) atomicAdd(&lhist[dst[e] >> 5], 1);
    __syncthreads();
    for (int i = t; i < NBKT; i += 256) {
        int h = lhist[i];
        if (h) atomicAdd(&bcnt[i], h);
    }
}

__global__ void k_pscan(const int* __restrict__ bcnt, int* __restrict__ bbase,
                        int* __restrict__ bcursor) {
    __shared__ int ts[256];
    int t = threadIdx.x;
    int i0 = t * PSC_NPT;
    int s = 0;
    for (int i = 0; i < PSC_NPT; i++) {
        int idx = i0 + i;
        if (idx < NBKT) s += bcnt[idx];
    }
    ts[t] = s;
    __syncthreads();
    for (int off = 1; off < 256; off <<= 1) {
        int val = (t >= off) ? ts[t - off] : 0;
        __syncthreads();
        ts[t] += val;
        __syncthreads();
    }
    int run = ts[t] - s;                // exclusive prefix
    for (int i = 0; i < PSC_NPT; i++) {
        int idx = i0 + i;
        if (idx < NBKT) {
            bbase[idx] = run;
            bcursor[idx] = run;
            run += bcnt[idx];
        }
    }
}

__launch_bounds__(256)
__global__ void k_pfill(const int* __restrict__ src, const int* __restrict__ dst,
                        int* __restrict__ bcursor, unsigned int* __restrict__ pairs, int E) {
    __shared__ int lhist[NBKT];
    __shared__ int lbase[NBKT];
    int t = threadIdx.x;
    int chunk = (E + PFB - 1) / PFB;
    int c0 = blockIdx.x * chunk;
    int c1 = min(E, c0 + chunk);
    for (int i = t; i < NBKT; i += 256) lhist[i] = 0;
    __syncthreads();
    for (int e = c0 + t; e < c1; e += 256) atomicAdd(&lhist[dst[e] >> 5], 1);
    __syncthreads();
    for (int i = t; i < NBKT; i += 256) {
        int h = lhist[i];
        lbase[i] = h ? atomicAdd(&bcursor[i], h) : 0;
        lhist[i] = 0;                   // reuse as local cursor
    }
    __syncthreads();
    for (int e = c0 + t; e < c1; e += 256) {
        int d = dst[e];
        int bkt = d >> 5;
        int rank = atomicAdd(&lhist[bkt], 1);
        pairs[lbase[bkt] + rank] = ((unsigned)src[e] << 5) | (unsigned)(d & 31);
    }
}

// ===== fused: per 32-node bucket, LDS-sort pairs, VGPR-gather rows into LDS A-tile,
//       then MFMA GEMM (h = A @ Wb^T + b) + BN stats, store bf16 h =====
__launch_bounds__(256, 4)
__global__ void k_agg_gemm(const ushort4* __restrict__ xb4, const unsigned int* __restrict__ pairs,
                           const int* __restrict__ bbase, const int* __restrict__ bcnt,
                           const unsigned short* __restrict__ Wb, const float* __restrict__ bias,
                           unsigned short* __restrict__ hb, float* __restrict__ stat) {
    __shared__ unsigned int lp[ECAP];
    __shared__ int lhist[BKT];
    __shared__ int lofs[BKT + 1];
    __shared__ unsigned short As[BKT * NP];
    __shared__ float ssum[HDIM];
    __shared__ float ssq[HDIM];
    const int t = threadIdx.x;
    const int lane = t & 63;
    const int wid = t >> 6;
    const int q = lane >> 4;
    const int l16 = lane & 15;
    const int v0 = blockIdx.x * BKT;
    const int ebeg = bbase[blockIdx.x];
    const int ecnt = bcnt[blockIdx.x];
    const int vrows = min(BKT, NN - v0);

    ssum[t] = 0.f;
    ssq[t] = 0.f;

    if (ecnt <= ECAP) {
        if (t < BKT) lhist[t] = 0;
        __syncthreads();
        for (int e = t; e < ecnt; e += 256)
            atomicAdd(&lhist[pairs[ebeg + e] & 31], 1);
        __syncthreads();
        if (t == 0) {
            int run = 0;
            for (int r = 0; r < BKT; r++) { lofs[r] = run; run += lhist[r]; }
            lofs[BKT] = run;
        }
        __syncthreads();
        if (t < BKT) lhist[t] = lofs[t];
        __syncthreads();
        for (int e = t; e < ecnt; e += 256) {
            unsigned int p = pairs[ebeg + e];
            int pos = atomicAdd(&lhist[p & 31], 1);
            lp[pos] = p;
        }
        __syncthreads();
        // gather: wave wid owns rows wid*8 .. wid*8+7
#pragma unroll
        for (int i = 0; i < 8; i++) {
            int r = wid * 8 + i;
            int v = v0 + r;
            if (v < NN) {
                ushort4 u0 = xb4[(size_t)v * 64 + lane];
                float a0 = b2f(u0.x), a1 = b2f(u0.y), a2 = b2f(u0.z), a3 = b2f(u0.w);
                int e0 = __builtin_amdgcn_readfirstlane(lofs[r]);
                int e1 = __builtin_amdgcn_readfirstlane(lofs[r + 1]);
                int e = e0;
                for (; e + 8 <= e1; e += 8) {
                    ushort4 u[8];
#pragma unroll
                    for (int j = 0; j < 8; j++)
                        u[j] = xb4[(size_t)(lp[e + j] >> 5) * 64 + lane];
#pragma unroll
                    for (int j = 0; j < 8; j++) {
                        a0 += b2f(u[j].x); a1 += b2f(u[j].y);
                        a2 += b2f(u[j].z); a3 += b2f(u[j].w);
                    }
                }
                for (; e + 4 <= e1; e += 4) {
                    ushort4 ua = xb4[(size_t)(lp[e] >> 5) * 64 + lane];
                    ushort4 ub = xb4[(size_t)(lp[e + 1] >> 5) * 64 + lane];
                    ushort4 uc = xb4[(size_t)(lp[e + 2] >> 5) * 64 + lane];
                    ushort4 ud = xb4[(size_t)(lp[e + 3] >> 5) * 64 + lane];
                    a0 += (b2f(ua.x) + b2f(ub.x)) + (b2f(uc.x) + b2f(ud.x));
                    a1 += (b2f(ua.y) + b2f(ub.y)) + (b2f(uc.y) + b2f(ud.y));
                    a2 += (b2f(ua.z) + b2f(ub.z)) + (b2f(uc.z) + b2f(ud.z));
                    a3 += (b2f(ua.w) + b2f(ub.w)) + (b2f(uc.w) + b2f(ud.w));
                }
                for (; e < e1; e++) {
                    ushort4 ua = xb4[(size_t)(lp[e] >> 5) * 64 + lane];
                    a0 += b2f(ua.x); a1 += b2f(ua.y); a2 += b2f(ua.z); a3 += b2f(ua.w);
                }
                *(ushort4*)(As + r * NP + lane * 4) =
                    make_ushort4(f2b(a0), f2b(a1), f2b(a2), f2b(a3));
            } else {
                *(ushort4*)(As + r * NP + lane * 4) = make_ushort4(0, 0, 0, 0);
            }
        }
    } else {
        // statistically-unreachable overflow: scan full bucket list per owned row
#pragma unroll
        for (int i = 0; i < 8; i++) {
            int r = wid * 8 + i;
            int v = v0 + r;
            float a0 = 0.f, a1 = 0.f, a2 = 0.f, a3 = 0.f;
            if (v < NN) {
                ushort4 u0 = xb4[(size_t)v * 64 + lane];
                a0 = b2f(u0.x); a1 = b2f(u0.y); a2 = b2f(u0.z); a3 = b2f(u0.w);
                for (int e = 0; e < ecnt; e++) {
                    unsigned int p = pairs[ebeg + e];
                    if ((int)(p & 31) == r) {
                        ushort4 cu = xb4[(size_t)(p >> 5) * 64 + lane];
                        a0 += b2f(cu.x); a1 += b2f(cu.y); a2 += b2f(cu.z); a3 += b2f(cu.w);
                    }
                }
            }
            *(ushort4*)(As + r * NP + lane * 4) =
                make_ushort4(f2b(a0), f2b(a1), f2b(a2), f2b(a3));
        }
    }
    __syncthreads();

    // ---- MFMA GEMM on the 32xFDIM A-tile ----
    f32x4 acc[2][4];  // [m-tile][n-tile]
#pragma unroll
    for (int mt = 0; mt < 2; mt++)
#pragma unroll
        for (int nt = 0; nt < 4; nt++) acc[mt][nt] = (f32x4)0.f;

    const int w = wid;  // wave -> cols w*64..w*64+63
#pragma unroll
    for (int ks = 0; ks < 8; ks++) {
        const int kk = ks * 32;
        short8v af[2], bf_[4];
#pragma unroll
        for (int mt = 0; mt < 2; mt++)
            af[mt] = *(const short8v*)(As + (mt * 16 + l16) * NP + kk + q * 8);
#pragma unroll
        for (int nt = 0; nt < 4; nt++)
            bf_[nt] = *(const short8v*)(Wb + (size_t)(w * 64 + nt * 16 + l16) * FDIM + kk + q * 8);
#pragma unroll
        for (int mt = 0; mt < 2; mt++)
#pragma unroll
            for (int nt = 0; nt < 4; nt++)
                acc[mt][nt] = __builtin_amdgcn_mfma_f32_16x16x32_bf16(af[mt], bf_[nt], acc[mt][nt], 0, 0, 0);
    }

    // epilogue: bias, bf16 store, BN stats
#pragma unroll
    for (int nt = 0; nt < 4; nt++) {
        const int col = w * 64 + nt * 16 + l16;
        const float bcol = bias[col];
        float s = 0.f, qq = 0.f;
#pragma unroll
        for (int mt = 0; mt < 2; mt++) {
            const int rbase = mt * 16 + q * 4;
#pragma unroll
            for (int r = 0; r < 4; r++) {
                int row = rbase + r;
                if (row < vrows) {
                    float v = acc[mt][nt][r] + bcol;
                    hb[(size_t)(v0 + row) * FDIM + col] = f2b(v);
                    s += v;
                    qq += v * v;
                }
            }
        }
        atomicAdd(&ssum[col], s);
        atomicAdd(&ssq[col], qq);
    }
    __syncthreads();
    atomicAdd(&stat[t], ssum[t]);
    atomicAdd(&stat[256 + t], ssq[t]);
}

// ================= BN finalize + normalize =================
__global__ void k_final(const float* __restrict__ stat, const float* __restrict__ bn_w,
                        const float* __restrict__ bn_b, float* __restrict__ ss) {
    int j = threadIdx.x;
    const float inv_n = 1.0f / (float)NN;
    float mean = stat[j] * inv_n;
    float var = stat[256 + j] * inv_n - mean * mean;
    float sc = bn_w[j] * rsqrtf(var + BN_EPS);
    ss[j] = sc;
    ss[256 + j] = bn_b[j] - mean * sc;
}

__global__ void k_norm8(const ushort8v* __restrict__ hb8, const float* __restrict__ ss,
                        float4* __restrict__ out, int n8) {
    int i = blockIdx.x * blockDim.x + threadIdx.x;
    if (i >= n8) return;
    ushort8v u = hb8[i];
    int c8 = (i & 31) << 3;
    float4 sc0 = *(const float4*)(ss + c8);
    float4 sc1 = *(const float4*)(ss + c8 + 4);
    float4 sh0 = *(const float4*)(ss + 256 + c8);
    float4 sh1 = *(const float4*)(ss + 256 + c8 + 4);
    float4 v0, v1;
    v0.x = fmaf(b2f(u[0]), sc0.x, sh0.x);
    v0.y = fmaf(b2f(u[1]), sc0.y, sh0.y);
    v0.z = fmaf(b2f(u[2]), sc0.z, sh0.z);
    v0.w = fmaf(b2f(u[3]), sc0.w, sh0.w);
    v1.x = fmaf(b2f(u[4]), sc1.x, sh1.x);
    v1.y = fmaf(b2f(u[5]), sc1.y, sh1.y);
    v1.z = fmaf(b2f(u[6]), sc1.z, sh1.z);
    v1.w = fmaf(b2f(u[7]), sc1.w, sh1.w);
    out[i * 2 + 0] = v0;
    out[i * 2 + 1] = v1;
}

// ================= fallback fp32 path (rounds 1-2) =================
__global__ void k_hist(const int* __restrict__ dst, int* __restrict__ cnt, int E) {
    int e = blockIdx.x * blockDim.x + threadIdx.x;
    if (e < E) atomicAdd(&cnt[dst[e]], 1);
}
__global__ void k_scan1(const int* __restrict__ cnt, int* __restrict__ offs,
                        int* __restrict__ bsum) {
    __shared__ int ts[256];
    int t = threadIdx.x;
    int base = blockIdx.x * SCAN_CHUNK + t * 4;
    int v0 = (base + 0 < NN) ? cnt[base + 0] : 0;
    int v1 = (base + 1 < NN) ? cnt[base + 1] : 0;
    int v2 = (base + 2 < NN) ? cnt[base + 2] : 0;
    int v3 = (base + 3 < NN) ? cnt[base + 3] : 0;
    int tsum = v0 + v1 + v2 + v3;
    ts[t] = tsum;
    __syncthreads();
    for (int off = 1; off < 256; off <<= 1) {
        int val = (t >= off) ? ts[t - off] : 0;
        __syncthreads();
        ts[t] += val;
        __syncthreads();
    }
    int excl = ts[t] - tsum;
    if (t == 255) bsum[blockIdx.x] = ts[255];
    if (base + 0 < NN) offs[base + 0] = excl;
    if (base + 1 < NN) offs[base + 1] = excl + v0;
    if (base + 2 < NN) offs[base + 2] = excl + v0 + v1;
    if (base + 3 < NN) offs[base + 3] = excl + v0 + v1 + v2;
}
__global__ void k_scan2(int* __restrict__ bsum, int nb) {
    if (threadIdx.x == 0 && blockIdx.x == 0) {
        int run = 0;
        for (int i = 0; i < nb; i++) { int v = bsum[i]; bsum[i] = run; run += v; }
    }
}
__global__ void k_scan3(int* __restrict__ offs, const int* __restrict__ bsum,
                        int* __restrict__ cursor) {
    int i = blockIdx.x * blockDim.x + threadIdx.x;
    if (i >= NN) return;
    int o = offs[i] + bsum[i >> 10];
    offs[i] = o;
    cursor[i] = o;
}
__global__ void k_bucket(const int* __restrict__ src, const int* __restrict__ dst,
                         int* __restrict__ cursor, int* __restrict__ csr, int E) {
    int e = blockIdx.x * blockDim.x + threadIdx.x;
    if (e >= E) return;
    int pos = atomicAdd(&cursor[dst[e]], 1);
    csr[pos] = src[e];
}
__global__ void k_copy(const float4* __restrict__ x, float4* __restrict__ out, int n4) {
    int i = blockIdx.x * blockDim.x + threadIdx.x;
    if (i < n4) out[i] = x[i];
}
__global__ void k_scatter(const float* __restrict__ x, const int* __restrict__ src,
                          const int* __restrict__ dst, float* __restrict__ out, int E) {
    int t = blockIdx.x * blockDim.x + threadIdx.x;
    int e = t >> 6;
    if (e >= E) return;
    int c = (t & 63) << 2;
    long s = src[e], d = dst[e];
    const float4 v = *(const float4*)(x + s * FDIM + c);
    float* o = out + d * FDIM + c;
    atomicAdd(o + 0, v.x);
    atomicAdd(o + 1, v.y);
    atomicAdd(o + 2, v.z);
    atomicAdd(o + 3, v.w);
}
__launch_bounds__(256)
__global__ void k_gather(const float4* __restrict__ x, const int* __restrict__ offs,
                         const int* __restrict__ cnt, const int* __restrict__ csr,
                         float4* __restrict__ out) {
    int v = blockIdx.x * 4 + (threadIdx.x >> 6);
    if (v >= NN) return;
    int lane = threadIdx.x & 63;
    int beg = __builtin_amdgcn_readfirstlane(offs[v]);
    int d   = __builtin_amdgcn_readfirstlane(cnt[v]);
    float4 acc = x[(size_t)v * 64 + lane];
    int i = 0;
    for (; i + 4 <= d; i += 4) {
        int s0 = csr[beg + i], s1 = csr[beg + i + 1];
        int s2 = csr[beg + i + 2], s3 = csr[beg + i + 3];
        float4 a = x[(size_t)s0 * 64 + lane];
        float4 b = x[(size_t)s1 * 64 + lane];
        float4 c = x[(size_t)s2 * 64 + lane];
        float4 e = x[(size_t)s3 * 64 + lane];
        acc.x += (a.x + b.x) + (c.x + e.x);
        acc.y += (a.y + b.y) + (c.y + e.y);
        acc.z += (a.z + b.z) + (c.z + e.z);
        acc.w += (a.w + b.w) + (c.w + e.w);
    }
    for (; i < d; i++) {
        int s = csr[beg + i];
        float4 a = x[(size_t)s * 64 + lane];
        acc.x += a.x; acc.y += a.y; acc.z += a.z; acc.w += a.w;
    }
    out[(size_t)v * 64 + lane] = acc;
}
__launch_bounds__(256)
__global__ void k_gemm_stats(float* __restrict__ h,
                             const float* __restrict__ W,
                             const float* __restrict__ bias,
                             float* __restrict__ stat) {
    __shared__ float hs[RB * FDIM];
    __shared__ float wt[KC * HDIM];
    const int j = threadIdx.x;
    const int c = j & 63;
    const int g = j >> 6;
    const long row0 = (long)blockIdx.x * RB;
    const int vrows = min(RB, NN - (int)row0);
    const int vf4 = vrows * (FDIM / 4);

    float4* hsv = (float4*)hs;
    const float4* hv = (const float4*)(h + row0 * FDIM);
#pragma unroll
    for (int i = 0; i < (RB * FDIM / 4) / 256; i++) {
        int f4 = j + i * 256;
        hsv[f4] = (f4 < vf4) ? hv[f4] : make_float4(0.f, 0.f, 0.f, 0.f);
    }
    __syncthreads();

    float acc[8][4];
#pragma unroll
    for (int r = 0; r < 8; r++)
#pragma unroll
        for (int qi = 0; qi < 4; qi++) acc[r][qi] = 0.f;

    for (int kb = 0; kb < FDIM; kb += KC) {
        __syncthreads();
#pragma unroll
        for (int i = 0; i < KC / 4; i++) {
            float4 w4 = *(const float4*)(W + (size_t)j * FDIM + kb + i * 4);
            wt[(i * 4 + 0) * HDIM + j] = w4.x;
            wt[(i * 4 + 1) * HDIM + j] = w4.y;
            wt[(i * 4 + 2) * HDIM + j] = w4.z;
            wt[(i * 4 + 3) * HDIM + j] = w4.w;
        }
        __syncthreads();
#pragma unroll
        for (int k = 0; k < KC; k++) {
            float4 wv = *(const float4*)(wt + k * HDIM + c * 4);
#pragma unroll
            for (int r = 0; r < 8; r++) {
                float hval = hs[(g * 8 + r) * FDIM + kb + k];
                acc[r][0] = fmaf(hval, wv.x, acc[r][0]);
                acc[r][1] = fmaf(hval, wv.y, acc[r][1]);
                acc[r][2] = fmaf(hval, wv.z, acc[r][2]);
                acc[r][3] = fmaf(hval, wv.w, acc[r][3]);
            }
        }
    }
    __syncthreads();
    wt[j] = 0.f;
    wt[256 + j] = 0.f;
    __syncthreads();

    float4 bv = *(const float4*)(bias + c * 4);
    float s0 = 0, s1 = 0, s2 = 0, s3 = 0, q0 = 0, q1 = 0, q2 = 0, q3 = 0;
#pragma unroll
    for (int r = 0; r < 8; r++) {
        int row = g * 8 + r;
        if (row < vrows) {
            float4 v;
            v.x = acc[r][0] + bv.x;
            v.y = acc[r][1] + bv.y;
            v.z = acc[r][2] + bv.z;
            v.w = acc[r][3] + bv.w;
            *(float4*)(h + (row0 + row) * FDIM + c * 4) = v;
            s0 += v.x; s1 += v.y; s2 += v.z; s3 += v.w;
            q0 += v.x * v.x; q1 += v.y * v.y; q2 += v.z * v.z; q3 += v.w * v.w;
        }
    }
    atomicAdd(&wt[c * 4 + 0], s0);
    atomicAdd(&wt[c * 4 + 1], s1);
    atomicAdd(&wt[c * 4 + 2], s2);
    atomicAdd(&wt[c * 4 + 3], s3);
    atomicAdd(&wt[256 + c * 4 + 0], q0);
    atomicAdd(&wt[256 + c * 4 + 1], q1);
    atomicAdd(&wt[256 + c * 4 + 2], q2);
    atomicAdd(&wt[256 + c * 4 + 3], q3);
    __syncthreads();
    atomicAdd(&stat[j], wt[j]);
    atomicAdd(&stat[256 + j], wt[256 + j]);
}
__global__ void k_norm(float* __restrict__ out, const float* __restrict__ ss, int n4) {
    int i = blockIdx.x * blockDim.x + threadIdx.x;
    if (i >= n4) return;
    float4 v = ((float4*)out)[i];
    int c4 = (i & 63) << 2;
    float4 sc = *(const float4*)(ss + c4);
    float4 sh = *(const float4*)(ss + 256 + c4);
    v.x = fmaf(v.x, sc.x, sh.x);
    v.y = fmaf(v.y, sc.y, sh.y);
    v.z = fmaf(v.z, sc.z, sh.z);
    v.w = fmaf(v.w, sc.w, sh.w);
    ((float4*)out)[i] = v;
}

extern "C" void kernel_launch(void* const* d_in, const int* in_sizes, int n_in,
                              void* d_out, int out_size, void* d_ws, size_t ws_size,
                              hipStream_t stream) {
    const float* x   = (const float*)d_in[0];
    const int*   ei  = (const int*)d_in[1];
    const float* W   = (const float*)d_in[2];
    const float* b   = (const float*)d_in[3];
    const float* bnw = (const float*)d_in[4];
    const float* bnb = (const float*)d_in[5];
    float* out = (float*)d_out;
    char* ws = (char*)d_ws;
    const int E = in_sizes[1] / 2;
    const int n4 = NN * FDIM / 4;
    const int n8 = NN * FDIM / 8;
    const int* src = ei;
    const int* dst = ei + E;

    // ---- fast-path ws layout ----
    size_t off = 0;
    float* stat = (float*)(ws + off);          off += 4096;
    int* bcnt   = (int*)(ws + off);            off += 8192;
    int* bbase  = (int*)(ws + off);            off += 8192;
    int* bcur   = (int*)(ws + off);            off += 8192;
    unsigned int* pairs = (unsigned int*)(ws + off); off += (size_t)E * 4;
    off = (off + 255) & ~(size_t)255;
    unsigned short* Wb = (unsigned short*)(ws + off); off += 131072;
    unsigned short* xb = (unsigned short*)(ws + off); off += (size_t)NN * FDIM * 2;
    unsigned short* hb = (unsigned short*)(ws + off); off += (size_t)NN * FDIM * 2;
    const size_t need_fast = off;

    // ---- fallback (fp32 CSR) layout ----
    size_t foff = 0;
    float* fstat  = (float*)(ws + foff); foff += 4096;
    int*   cnt    = (int*)(ws + foff);   foff += 204800;
    int*   offs   = (int*)(ws + foff);   foff += 204800;
    int*   cursor = (int*)(ws + foff);   foff += 204800;
    int*   bsum   = (int*)(ws + foff);   foff += 4096;
    int*   csr    = (int*)(ws + foff);   foff += (size_t)E * 4;
    const size_t need_mid = foff;

    if (ws_size >= need_fast) {
        hipMemsetAsync(stat, 0, 2 * 256 * sizeof(float), stream);
        hipMemsetAsync(bcnt, 0, NBKT * sizeof(int), stream);
        const int nw4 = HDIM * FDIM / 4;
        k_cvt2<<<(n4 + nw4 + 255) / 256, 256, 0, stream>>>((const float4*)x, (const float4*)W,
                                                           (ushort4*)xb, (ushort4*)Wb, n4, nw4);
        k_phist<<<256, 256, 0, stream>>>(dst, bcnt, E);
        k_pscan<<<1, 256, 0, stream>>>(bcnt, bbase, bcur);
        k_pfill<<<PFB, 256, 0, stream>>>(src, dst, bcur, pairs, E);
        k_agg_gemm<<<NBKT, 256, 0, stream>>>((const ushort4*)xb, pairs, bbase, bcnt,
                                             Wb, b, hb, stat);
        k_final<<<1, 256, 0, stream>>>(stat, bnw, bnb, stat + 512);
        k_norm8<<<(n8 + 255) / 256, 256, 0, stream>>>((const ushort8v*)hb, stat + 512,
                                                      (float4*)out, n8);
    } else if (ws_size >= need_mid) {
        hipMemsetAsync(fstat, 0, 2 * 256 * sizeof(float), stream);
        hipMemsetAsync(cnt, 0, NN * sizeof(int), stream);
        k_hist<<<(E + 255) / 256, 256, 0, stream>>>(dst, cnt, E);
        k_scan1<<<NBLK_SCAN, 256, 0, stream>>>(cnt, offs, bsum);
        k_scan2<<<1, 64, 0, stream>>>(bsum, NBLK_SCAN);
        k_scan3<<<(NN + 255) / 256, 256, 0, stream>>>(offs, bsum, cursor);
        k_bucket<<<(E + 255) / 256, 256, 0, stream>>>(src, dst, cursor, csr, E);
        k_gather<<<(NN + 3) / 4, 256, 0, stream>>>((const float4*)x, offs, cnt, csr,
                                                   (float4*)out);
        k_gemm_stats<<<(NN + RB - 1) / RB, 256, 0, stream>>>(out, W, b, fstat);
        k_final<<<1, 256, 0, stream>>>(fstat, bnw, bnb, fstat + 512);
        k_norm<<<(n4 + 255) / 256, 256, 0, stream>>>(out, fstat + 512, n4);
    } else {
        hipMemsetAsync(fstat, 0, 2 * 256 * sizeof(float), stream);
        k_copy<<<(n4 + 255) / 256, 256, 0, stream>>>((const float4*)x, (float4*)out, n4);
        long threads = (long)E * 64;
        k_scatter<<<(int)((threads + 255) / 256), 256, 0, stream>>>(x, src, dst, out, E);
        k_gemm_stats<<<(NN + RB - 1) / RB, 256, 0, stream>>>(out, W, b, fstat);
        k_final<<<1, 256, 0, stream>>>(fstat, bnw, bnb, fstat + 512);
        k_norm<<<(n4 + 255) / 256, 256, 0, stream>>>(out, fstat + 512, n4);
    }
}

// Round 7
// 325.790 us; speedup vs baseline: 1.2472x; 1.2472x over previous
//
#include <hip/hip_runtime.h>

#define NN 50000
#define FDIM 256
#define HDIM 256
#define BN_EPS 1e-5f
#define RB 32     // rows per fallback GEMM block
#define KC 16
#define NP 264    // padded LDS row stride (bf16 elems)
#define SCAN_CHUNK 1024
#define NBLK_SCAN ((NN + SCAN_CHUNK - 1) / SCAN_CHUNK)

// partition params
#define BKT 32                 // nodes per bucket == fused GEMM tile rows
#define NBKT 1563              // ceil(NN/32)
#define ECAP 1280              // LDS pair capacity in k_agg (mean 1024, ~8 sigma)
#define PFB 256                // fill blocks
#define SBUF_CAP 6400          // per-block sorted chunk capacity (E=1.6M -> 6250)
#define PSC_NPT 7              // 7*256 = 1792 >= NBKT
// pair encoding: [bkt:11][src:16][ldst:5]
#define PAIR_SRC(p) (((p) >> 5) & 0xFFFFu)
#define PAIR_LDST(p) ((p) & 31u)

typedef __attribute__((ext_vector_type(8))) short short8v;
typedef __attribute__((ext_vector_type(8))) unsigned short ushort8v;
typedef __attribute__((ext_vector_type(4))) float f32x4;

__device__ __forceinline__ float b2f(unsigned short u) {
    return __uint_as_float(((unsigned)u) << 16);
}
__device__ __forceinline__ unsigned short f2b(float f) {  // RNE
    unsigned u = __float_as_uint(f);
    return (unsigned short)((u + 0x7FFFu + ((u >> 16) & 1u)) >> 16);
}

// ================= fp32 -> bf16 convert (x and W in one launch) =================
__global__ void k_cvt2(const float4* __restrict__ x, const float4* __restrict__ W,
                       ushort4* __restrict__ xb, ushort4* __restrict__ Wb,
                       int nx4, int nw4) {
    int i = blockIdx.x * blockDim.x + threadIdx.x;
    if (i < nx4) {
        float4 v = x[i];
        xb[i] = make_ushort4(f2b(v.x), f2b(v.y), f2b(v.z), f2b(v.w));
    } else {
        int j = i - nx4;
        if (j < nw4) {
            float4 v = W[j];
            Wb[j] = make_ushort4(f2b(v.x), f2b(v.y), f2b(v.z), f2b(v.w));
        }
    }
}

// ================= bucket partition (counting sort by dst>>5) =================
__launch_bounds__(256)
__global__ void k_phist(const int* __restrict__ dst, int* __restrict__ bcnt, int E) {
    __shared__ int lhist[NBKT];
    int t = threadIdx.x;
    int chunk = (E + 255) / 256;       // grid = 256 blocks
    int c0 = blockIdx.x * chunk;
    int c1 = min(E, c0 + chunk);
    for (int i = t; i < NBKT; i += 256) lhist[i] = 0;
    __syncthreads();
    for (int e = c0 + t; e < c1; e += 256) atomicAdd(&lhist[dst[e] >> 5], 1);
    __syncthreads();
    for (int i = t; i < NBKT; i += 256) {
        int h = lhist[i];
        if (h) atomicAdd(&bcnt[i], h);
    }
}

__global__ void k_pscan(const int* __restrict__ bcnt, int* __restrict__ bbase,
                        int* __restrict__ bcursor) {
    __shared__ int ts[256];
    int t = threadIdx.x;
    int i0 = t * PSC_NPT;
    int s = 0;
    for (int i = 0; i < PSC_NPT; i++) {
        int idx = i0 + i;
        if (idx < NBKT) s += bcnt[idx];
    }
    ts[t] = s;
    __syncthreads();
    for (int off = 1; off < 256; off <<= 1) {
        int val = (t >= off) ? ts[t - off] : 0;
        __syncthreads();
        ts[t] += val;
        __syncthreads();
    }
    int run = ts[t] - s;                // exclusive prefix
    for (int i = 0; i < PSC_NPT; i++) {
        int idx = i0 + i;
        if (idx < NBKT) {
            bbase[idx] = run;
            bcursor[idx] = run;
            run += bcnt[idx];
        }
    }
}

// ---- sorted-write fill: LDS counting sort per chunk, then coalesced write-out ----
__launch_bounds__(256)
__global__ void k_pfill_sort(const int* __restrict__ src, const int* __restrict__ dst,
                             int* __restrict__ bcursor, unsigned int* __restrict__ pairs,
                             int E) {
    __shared__ int lhist[NBKT];         // counts -> cursor -> delta
    __shared__ int lofs[NBKT];          // local exclusive offsets
    __shared__ int ts[256];
    __shared__ unsigned int sbuf[SBUF_CAP];
    int t = threadIdx.x;
    int chunk = (E + PFB - 1) / PFB;
    int c0 = blockIdx.x * chunk;
    int c1 = min(E, c0 + chunk);
    int n = c1 - c0;

    for (int i = t; i < NBKT; i += 256) lhist[i] = 0;
    __syncthreads();
    // phase 1: histogram
    for (int e = c0 + t; e < c1; e += 256) atomicAdd(&lhist[dst[e] >> 5], 1);
    __syncthreads();
    // phase 2: block scan of lhist -> lofs (exclusive); lhist becomes cursor
    {
        int i0 = t * PSC_NPT;
        int s = 0;
        int loc[PSC_NPT];
        for (int i = 0; i < PSC_NPT; i++) {
            int idx = i0 + i;
            loc[i] = (idx < NBKT) ? lhist[idx] : 0;
            s += loc[i];
        }
        ts[t] = s;
        __syncthreads();
        for (int off = 1; off < 256; off <<= 1) {
            int val = (t >= off) ? ts[t - off] : 0;
            __syncthreads();
            ts[t] += val;
            __syncthreads();
        }
        int run = ts[t] - s;
        for (int i = 0; i < PSC_NPT; i++) {
            int idx = i0 + i;
            if (idx < NBKT) {
                lofs[idx] = run;
                run += loc[i];
            }
        }
    }
    __syncthreads();
    if (t < 256) {}  // keep structure
    for (int i = t; i < NBKT; i += 256) lhist[i] = lofs[i];  // cursor = base
    __syncthreads();
    // phase 3: place into sorted LDS buffer
    for (int e = c0 + t; e < c1; e += 256) {
        int d = dst[e];
        unsigned bkt = (unsigned)d >> 5;
        int rank = atomicAdd(&lhist[bkt], 1);
        sbuf[rank] = (bkt << 21) | ((unsigned)src[e] << 5) | ((unsigned)d & 31u);
    }
    __syncthreads();
    // phase 4: reserve global runs; lhist becomes delta = gbase - lofs
    for (int i = t; i < NBKT; i += 256) {
        int cnt = lhist[i] - lofs[i];
        int gb = cnt ? atomicAdd(&bcursor[i], cnt) : 0;
        lhist[i] = gb - lofs[i];
    }
    __syncthreads();
    // phase 5: coalesced write-out (consecutive j in same bucket -> consecutive dest)
    for (int j = t; j < n; j += 256) {
        unsigned int p = sbuf[j];
        pairs[j + lhist[p >> 21]] = p;
    }
}

// ---- basic fill fallback (if chunk exceeds SBUF_CAP) ----
__launch_bounds__(256)
__global__ void k_pfill(const int* __restrict__ src, const int* __restrict__ dst,
                        int* __restrict__ bcursor, unsigned int* __restrict__ pairs, int E) {
    __shared__ int lhist[NBKT];
    __shared__ int lbase[NBKT];
    int t = threadIdx.x;
    int chunk = (E + PFB - 1) / PFB;
    int c0 = blockIdx.x * chunk;
    int c1 = min(E, c0 + chunk);
    for (int i = t; i < NBKT; i += 256) lhist[i] = 0;
    __syncthreads();
    for (int e = c0 + t; e < c1; e += 256) atomicAdd(&lhist[dst[e] >> 5], 1);
    __syncthreads();
    for (int i = t; i < NBKT; i += 256) {
        int h = lhist[i];
        lbase[i] = h ? atomicAdd(&bcursor[i], h) : 0;
        lhist[i] = 0;
    }
    __syncthreads();
    for (int e = c0 + t; e < c1; e += 256) {
        int d = dst[e];
        unsigned bkt = (unsigned)d >> 5;
        int rank = atomicAdd(&lhist[bkt], 1);
        pairs[lbase[bkt] + rank] = (bkt << 21) | ((unsigned)src[e] << 5) | ((unsigned)d & 31u);
    }
}

// ===== fused: per 32-node bucket, LDS-sort pairs, VGPR-gather rows into LDS A-tile,
//       then MFMA GEMM (h = A @ Wb^T + b) + BN stats, store bf16 h =====
__launch_bounds__(256, 6)
__global__ void k_agg_gemm(const ushort4* __restrict__ xb4, const unsigned int* __restrict__ pairs,
                           const int* __restrict__ bbase, const int* __restrict__ bcnt,
                           const unsigned short* __restrict__ Wb, const float* __restrict__ bias,
                           unsigned short* __restrict__ hb, float* __restrict__ stat) {
    __shared__ unsigned int lp[ECAP];
    __shared__ int lhist[BKT];
    __shared__ int lofs[BKT + 1];
    __shared__ unsigned short As[BKT * NP];
    __shared__ float ssum[HDIM];
    __shared__ float ssq[HDIM];
    const int t = threadIdx.x;
    const int lane = t & 63;
    const int wid = t >> 6;
    const int q = lane >> 4;
    const int l16 = lane & 15;
    const int v0 = blockIdx.x * BKT;
    const int ebeg = bbase[blockIdx.x];
    const int ecnt = bcnt[blockIdx.x];
    const int vrows = min(BKT, NN - v0);

    ssum[t] = 0.f;
    ssq[t] = 0.f;

    if (ecnt <= ECAP) {
        if (t < BKT) lhist[t] = 0;
        __syncthreads();
        for (int e = t; e < ecnt; e += 256)
            atomicAdd(&lhist[PAIR_LDST(pairs[ebeg + e])], 1);
        __syncthreads();
        if (t == 0) {
            int run = 0;
            for (int r = 0; r < BKT; r++) { lofs[r] = run; run += lhist[r]; }
            lofs[BKT] = run;
        }
        __syncthreads();
        if (t < BKT) lhist[t] = lofs[t];
        __syncthreads();
        for (int e = t; e < ecnt; e += 256) {
            unsigned int p = pairs[ebeg + e];
            int pos = atomicAdd(&lhist[PAIR_LDST(p)], 1);
            lp[pos] = p;
        }
        __syncthreads();
        // gather: wave wid owns rows wid*8 .. wid*8+7
#pragma unroll
        for (int i = 0; i < 8; i++) {
            int r = wid * 8 + i;
            int v = v0 + r;
            if (v < NN) {
                ushort4 u0 = xb4[(size_t)v * 64 + lane];
                float a0 = b2f(u0.x), a1 = b2f(u0.y), a2 = b2f(u0.z), a3 = b2f(u0.w);
                int e0 = __builtin_amdgcn_readfirstlane(lofs[r]);
                int e1 = __builtin_amdgcn_readfirstlane(lofs[r + 1]);
                int e = e0;
                for (; e + 16 <= e1; e += 16) {
                    ushort4 u[16];
#pragma unroll
                    for (int j = 0; j < 16; j++)
                        u[j] = xb4[(size_t)PAIR_SRC(lp[e + j]) * 64 + lane];
#pragma unroll
                    for (int j = 0; j < 16; j++) {
                        a0 += b2f(u[j].x); a1 += b2f(u[j].y);
                        a2 += b2f(u[j].z); a3 += b2f(u[j].w);
                    }
                }
                for (; e + 4 <= e1; e += 4) {
                    ushort4 ua = xb4[(size_t)PAIR_SRC(lp[e]) * 64 + lane];
                    ushort4 ub = xb4[(size_t)PAIR_SRC(lp[e + 1]) * 64 + lane];
                    ushort4 uc = xb4[(size_t)PAIR_SRC(lp[e + 2]) * 64 + lane];
                    ushort4 ud = xb4[(size_t)PAIR_SRC(lp[e + 3]) * 64 + lane];
                    a0 += (b2f(ua.x) + b2f(ub.x)) + (b2f(uc.x) + b2f(ud.x));
                    a1 += (b2f(ua.y) + b2f(ub.y)) + (b2f(uc.y) + b2f(ud.y));
                    a2 += (b2f(ua.z) + b2f(ub.z)) + (b2f(uc.z) + b2f(ud.z));
                    a3 += (b2f(ua.w) + b2f(ub.w)) + (b2f(uc.w) + b2f(ud.w));
                }
                for (; e < e1; e++) {
                    ushort4 ua = xb4[(size_t)PAIR_SRC(lp[e]) * 64 + lane];
                    a0 += b2f(ua.x); a1 += b2f(ua.y); a2 += b2f(ua.z); a3 += b2f(ua.w);
                }
                *(ushort4*)(As + r * NP + lane * 4) =
                    make_ushort4(f2b(a0), f2b(a1), f2b(a2), f2b(a3));
            } else {
                *(ushort4*)(As + r * NP + lane * 4) = make_ushort4(0, 0, 0, 0);
            }
        }
    } else {
        // statistically-unreachable overflow: scan full bucket list per owned row
#pragma unroll
        for (int i = 0; i < 8; i++) {
            int r = wid * 8 + i;
            int v = v0 + r;
            float a0 = 0.f, a1 = 0.f, a2 = 0.f, a3 = 0.f;
            if (v < NN) {
                ushort4 u0 = xb4[(size_t)v * 64 + lane];
                a0 = b2f(u0.x); a1 = b2f(u0.y); a2 = b2f(u0.z); a3 = b2f(u0.w);
                for (int e = 0; e < ecnt; e++) {
                    unsigned int p = pairs[ebeg + e];
                    if ((int)PAIR_LDST(p) == r) {
                        ushort4 cu = xb4[(size_t)PAIR_SRC(p) * 64 + lane];
                        a0 += b2f(cu.x); a1 += b2f(cu.y); a2 += b2f(cu.z); a3 += b2f(cu.w);
                    }
                }
            }
            *(ushort4*)(As + r * NP + lane * 4) =
                make_ushort4(f2b(a0), f2b(a1), f2b(a2), f2b(a3));
        }
    }
    __syncthreads();

    // ---- MFMA GEMM on the 32xFDIM A-tile ----
    f32x4 acc[2][4];  // [m-tile][n-tile]
#pragma unroll
    for (int mt = 0; mt < 2; mt++)
#pragma unroll
        for (int nt = 0; nt < 4; nt++) acc[mt][nt] = (f32x4)0.f;

    const int w = wid;  // wave -> cols w*64..w*64+63
#pragma unroll
    for (int ks = 0; ks < 8; ks++) {
        const int kk = ks * 32;
        short8v af[2], bf_[4];
#pragma unroll
        for (int mt = 0; mt < 2; mt++)
            af[mt] = *(const short8v*)(As + (mt * 16 + l16) * NP + kk + q * 8);
#pragma unroll
        for (int nt = 0; nt < 4; nt++)
            bf_[nt] = *(const short8v*)(Wb + (size_t)(w * 64 + nt * 16 + l16) * FDIM + kk + q * 8);
#pragma unroll
        for (int mt = 0; mt < 2; mt++)
#pragma unroll
            for (int nt = 0; nt < 4; nt++)
                acc[mt][nt] = __builtin_amdgcn_mfma_f32_16x16x32_bf16(af[mt], bf_[nt], acc[mt][nt], 0, 0, 0);
    }

    // epilogue: bias, bf16 store, BN stats
#pragma unroll
    for (int nt = 0; nt < 4; nt++) {
        const int col = w * 64 + nt * 16 + l16;
        const float bcol = bias[col];
        float s = 0.f, qq = 0.f;
#pragma unroll
        for (int mt = 0; mt < 2; mt++) {
            const int rbase = mt * 16 + q * 4;
#pragma unroll
            for (int r = 0; r < 4; r++) {
                int row = rbase + r;
                if (row < vrows) {
                    float v = acc[mt][nt][r] + bcol;
                    hb[(size_t)(v0 + row) * FDIM + col] = f2b(v);
                    s += v;
                    qq += v * v;
                }
            }
        }
        atomicAdd(&ssum[col], s);
        atomicAdd(&ssq[col], qq);
    }
    __syncthreads();
    atomicAdd(&stat[t], ssum[t]);
    atomicAdd(&stat[256 + t], ssq[t]);
}

// ================= BN finalize + normalize =================
__global__ void k_final(const float* __restrict__ stat, const float* __restrict__ bn_w,
                        const float* __restrict__ bn_b, float* __restrict__ ss) {
    int j = threadIdx.x;
    const float inv_n = 1.0f / (float)NN;
    float mean = stat[j] * inv_n;
    float var = stat[256 + j] * inv_n - mean * mean;
    float sc = bn_w[j] * rsqrtf(var + BN_EPS);
    ss[j] = sc;
    ss[256 + j] = bn_b[j] - mean * sc;
}

__global__ void k_norm8(const ushort8v* __restrict__ hb8, const float* __restrict__ ss,
                        float4* __restrict__ out, int n8) {
    int i = blockIdx.x * blockDim.x + threadIdx.x;
    if (i >= n8) return;
    ushort8v u = hb8[i];
    int c8 = (i & 31) << 3;
    float4 sc0 = *(const float4*)(ss + c8);
    float4 sc1 = *(const float4*)(ss + c8 + 4);
    float4 sh0 = *(const float4*)(ss + 256 + c8);
    float4 sh1 = *(const float4*)(ss + 256 + c8 + 4);
    float4 v0, v1;
    v0.x = fmaf(b2f(u[0]), sc0.x, sh0.x);
    v0.y = fmaf(b2f(u[1]), sc0.y, sh0.y);
    v0.z = fmaf(b2f(u[2]), sc0.z, sh0.z);
    v0.w = fmaf(b2f(u[3]), sc0.w, sh0.w);
    v1.x = fmaf(b2f(u[4]), sc1.x, sh1.x);
    v1.y = fmaf(b2f(u[5]), sc1.y, sh1.y);
    v1.z = fmaf(b2f(u[6]), sc1.z, sh1.z);
    v1.w = fmaf(b2f(u[7]), sc1.w, sh1.w);
    out[i * 2 + 0] = v0;
    out[i * 2 + 1] = v1;
}

// ================= fallback fp32 path (rounds 1-2) =================
__global__ void k_hist(const int* __restrict__ dst, int* __restrict__ cnt, int E) {
    int e = blockIdx.x * blockDim.x + threadIdx.x;
    if (e < E) atomicAdd(&cnt[dst[e]], 1);
}
__global__ void k_scan1(const int* __restrict__ cnt, int* __restrict__ offs,
                        int* __restrict__ bsum) {
    __shared__ int ts[256];
    int t = threadIdx.x;
    int base = blockIdx.x * SCAN_CHUNK + t * 4;
    int v0 = (base + 0 < NN) ? cnt[base + 0] : 0;
    int v1 = (base + 1 < NN) ? cnt[base + 1] : 0;
    int v2 = (base + 2 < NN) ? cnt[base + 2] : 0;
    int v3 = (base + 3 < NN) ? cnt[base + 3] : 0;
    int tsum = v0 + v1 + v2 + v3;
    ts[t] = tsum;
    __syncthreads();
    for (int off = 1; off < 256; off <<= 1) {
        int val = (t >= off) ? ts[t - off] : 0;
        __syncthreads();
        ts[t] += val;
        __syncthreads();
    }
    int excl = ts[t] - tsum;
    if (t == 255) bsum[blockIdx.x] = ts[255];
    if (base + 0 < NN) offs[base + 0] = excl;
    if (base + 1 < NN) offs[base + 1] = excl + v0;
    if (base + 2 < NN) offs[base + 2] = excl + v0 + v1;
    if (base + 3 < NN) offs[base + 3] = excl + v0 + v1 + v2;
}
__global__ void k_scan2(int* __restrict__ bsum, int nb) {
    if (threadIdx.x == 0 && blockIdx.x == 0) {
        int run = 0;
        for (int i = 0; i < nb; i++) { int v = bsum[i]; bsum[i] = run; run += v; }
    }
}
__global__ void k_scan3(int* __restrict__ offs, const int* __restrict__ bsum,
                        int* __restrict__ cursor) {
    int i = blockIdx.x * blockDim.x + threadIdx.x;
    if (i >= NN) return;
    int o = offs[i] + bsum[i >> 10];
    offs[i] = o;
    cursor[i] = o;
}
__global__ void k_bucket(const int* __restrict__ src, const int* __restrict__ dst,
                         int* __restrict__ cursor, int* __restrict__ csr, int E) {
    int e = blockIdx.x * blockDim.x + threadIdx.x;
    if (e >= E) return;
    int pos = atomicAdd(&cursor[dst[e]], 1);
    csr[pos] = src[e];
}
__global__ void k_copy(const float4* __restrict__ x, float4* __restrict__ out, int n4) {
    int i = blockIdx.x * blockDim.x + threadIdx.x;
    if (i < n4) out[i] = x[i];
}
__global__ void k_scatter(const float* __restrict__ x, const int* __restrict__ src,
                          const int* __restrict__ dst, float* __restrict__ out, int E) {
    int t = blockIdx.x * blockDim.x + threadIdx.x;
    int e = t >> 6;
    if (e >= E) return;
    int c = (t & 63) << 2;
    long s = src[e], d = dst[e];
    const float4 v = *(const float4*)(x + s * FDIM + c);
    float* o = out + d * FDIM + c;
    atomicAdd(o + 0, v.x);
    atomicAdd(o + 1, v.y);
    atomicAdd(o + 2, v.z);
    atomicAdd(o + 3, v.w);
}
__launch_bounds__(256)
__global__ void k_gather(const float4* __restrict__ x, const int* __restrict__ offs,
                         const int* __restrict__ cnt, const int* __restrict__ csr,
                         float4* __restrict__ out) {
    int v = blockIdx.x * 4 + (threadIdx.x >> 6);
    if (v >= NN) return;
    int lane = threadIdx.x & 63;
    int beg = __builtin_amdgcn_readfirstlane(offs[v]);
    int d   = __builtin_amdgcn_readfirstlane(cnt[v]);
    float4 acc = x[(size_t)v * 64 + lane];
    int i = 0;
    for (; i + 4 <= d; i += 4) {
        int s0 = csr[beg + i], s1 = csr[beg + i + 1];
        int s2 = csr[beg + i + 2], s3 = csr[beg + i + 3];
        float4 a = x[(size_t)s0 * 64 + lane];
        float4 b = x[(size_t)s1 * 64 + lane];
        float4 c = x[(size_t)s2 * 64 + lane];
        float4 e = x[(size_t)s3 * 64 + lane];
        acc.x += (a.x + b.x) + (c.x + e.x);
        acc.y += (a.y + b.y) + (c.y + e.y);
        acc.z += (a.z + b.z) + (c.z + e.z);
        acc.w += (a.w + b.w) + (c.w + e.w);
    }
    for (; i < d; i++) {
        int s = csr[beg + i];
        float4 a = x[(size_t)s * 64 + lane];
        acc.x += a.x; acc.y += a.y; acc.z += a.z; acc.w += a.w;
    }
    out[(size_t)v * 64 + lane] = acc;
}
__launch_bounds__(256)
__global__ void k_gemm_stats(float* __restrict__ h,
                             const float* __restrict__ W,
                             const float* __restrict__ bias,
                             float* __restrict__ stat) {
    __shared__ float hs[RB * FDIM];
    __shared__ float wt[KC * HDIM];
    const int j = threadIdx.x;
    const int c = j & 63;
    const int g = j >> 6;
    const long row0 = (long)blockIdx.x * RB;
    const int vrows = min(RB, NN - (int)row0);
    const int vf4 = vrows * (FDIM / 4);

    float4* hsv = (float4*)hs;
    const float4* hv = (const float4*)(h + row0 * FDIM);
#pragma unroll
    for (int i = 0; i < (RB * FDIM / 4) / 256; i++) {
        int f4 = j + i * 256;
        hsv[f4] = (f4 < vf4) ? hv[f4] : make_float4(0.f, 0.f, 0.f, 0.f);
    }
    __syncthreads();

    float acc[8][4];
#pragma unroll
    for (int r = 0; r < 8; r++)
#pragma unroll
        for (int qi = 0; qi < 4; qi++) acc[r][qi] = 0.f;

    for (int kb = 0; kb < FDIM; kb += KC) {
        __syncthreads();
#pragma unroll
        for (int i = 0; i < KC / 4; i++) {
            float4 w4 = *(const float4*)(W + (size_t)j * FDIM + kb + i * 4);
            wt[(i * 4 + 0) * HDIM + j] = w4.x;
            wt[(i * 4 + 1) * HDIM + j] = w4.y;
            wt[(i * 4 + 2) * HDIM + j] = w4.z;
            wt[(i * 4 + 3) * HDIM + j] = w4.w;
        }
        __syncthreads();
#pragma unroll
        for (int k = 0; k < KC; k++) {
            float4 wv = *(const float4*)(wt + k * HDIM + c * 4);
#pragma unroll
            for (int r = 0; r < 8; r++) {
                float hval = hs[(g * 8 + r) * FDIM + kb + k];
                acc[r][0] = fmaf(hval, wv.x, acc[r][0]);
                acc[r][1] = fmaf(hval, wv.y, acc[r][1]);
                acc[r][2] = fmaf(hval, wv.z, acc[r][2]);
                acc[r][3] = fmaf(hval, wv.w, acc[r][3]);
            }
        }
    }
    __syncthreads();
    wt[j] = 0.f;
    wt[256 + j] = 0.f;
    __syncthreads();

    float4 bv = *(const float4*)(bias + c * 4);
    float s0 = 0, s1 = 0, s2 = 0, s3 = 0, q0 = 0, q1 = 0, q2 = 0, q3 = 0;
#pragma unroll
    for (int r = 0; r < 8; r++) {
        int row = g * 8 + r;
        if (row < vrows) {
            float4 v;
            v.x = acc[r][0] + bv.x;
            v.y = acc[r][1] + bv.y;
            v.z = acc[r][2] + bv.z;
            v.w = acc[r][3] + bv.w;
            *(float4*)(h + (row0 + row) * FDIM + c * 4) = v;
            s0 += v.x; s1 += v.y; s2 += v.z; s3 += v.w;
            q0 += v.x * v.x; q1 += v.y * v.y; q2 += v.z * v.z; q3 += v.w * v.w;
        }
    }
    atomicAdd(&wt[c * 4 + 0], s0);
    atomicAdd(&wt[c * 4 + 1], s1);
    atomicAdd(&wt[c * 4 + 2], s2);
    atomicAdd(&wt[c * 4 + 3], s3);
    atomicAdd(&wt[256 + c * 4 + 0], q0);
    atomicAdd(&wt[256 + c * 4 + 1], q1);
    atomicAdd(&wt[256 + c * 4 + 2], q2);
    atomicAdd(&wt[256 + c * 4 + 3], q3);
    __syncthreads();
    atomicAdd(&stat[j], wt[j]);
    atomicAdd(&stat[256 + j], wt[256 + j]);
}
__global__ void k_norm(float* __restrict__ out, const float* __restrict__ ss, int n4) {
    int i = blockIdx.x * blockDim.x + threadIdx.x;
    if (i >= n4) return;
    float4 v = ((float4*)out)[i];
    int c4 = (i & 63) << 2;
    float4 sc = *(const float4*)(ss + c4);
    float4 sh = *(const float4*)(ss + 256 + c4);
    v.x = fmaf(v.x, sc.x, sh.x);
    v.y = fmaf(v.y, sc.y, sh.y);
    v.z = fmaf(v.z, sc.z, sh.z);
    v.w = fmaf(v.w, sc.w, sh.w);
    ((float4*)out)[i] = v;
}

extern "C" void kernel_launch(void* const* d_in, const int* in_sizes, int n_in,
                              void* d_out, int out_size, void* d_ws, size_t ws_size,
                              hipStream_t stream) {
    const float* x   = (const float*)d_in[0];
    const int*   ei  = (const int*)d_in[1];
    const float* W   = (const float*)d_in[2];
    const float* b   = (const float*)d_in[3];
    const float* bnw = (const float*)d_in[4];
    const float* bnb = (const float*)d_in[5];
    float* out = (float*)d_out;
    char* ws = (char*)d_ws;
    const int E = in_sizes[1] / 2;
    const int n4 = NN * FDIM / 4;
    const int n8 = NN * FDIM / 8;
    const int* src = ei;
    const int* dst = ei + E;

    // ---- fast-path ws layout ----
    size_t off = 0;
    float* stat = (float*)(ws + off);          off += 4096;
    int* bcnt   = (int*)(ws + off);            off += 8192;
    int* bbase  = (int*)(ws + off);            off += 8192;
    int* bcur   = (int*)(ws + off);            off += 8192;
    unsigned int* pairs = (unsigned int*)(ws + off); off += (size_t)E * 4;
    off = (off + 255) & ~(size_t)255;
    unsigned short* Wb = (unsigned short*)(ws + off); off += 131072;
    unsigned short* xb = (unsigned short*)(ws + off); off += (size_t)NN * FDIM * 2;
    unsigned short* hb = (unsigned short*)(ws + off); off += (size_t)NN * FDIM * 2;
    const size_t need_fast = off;

    // ---- fallback (fp32 CSR) layout ----
    size_t foff = 0;
    float* fstat  = (float*)(ws + foff); foff += 4096;
    int*   cnt    = (int*)(ws + foff);   foff += 204800;
    int*   offs   = (int*)(ws + foff);   foff += 204800;
    int*   cursor = (int*)(ws + foff);   foff += 204800;
    int*   bsum   = (int*)(ws + foff);   foff += 4096;
    int*   csr    = (int*)(ws + foff);   foff += (size_t)E * 4;
    const size_t need_mid = foff;

    const bool src_fits = (NN <= 65536);   // pair encoding requires 16-bit src

    if (ws_size >= need_fast && src_fits) {
        hipMemsetAsync(stat, 0, 2 * 256 * sizeof(float), stream);
        hipMemsetAsync(bcnt, 0, NBKT * sizeof(int), stream);
        const int nw4 = HDIM * FDIM / 4;
        k_cvt2<<<(n4 + nw4 + 255) / 256, 256, 0, stream>>>((const float4*)x, (const float4*)W,
                                                           (ushort4*)xb, (ushort4*)Wb, n4, nw4);
        k_phist<<<256, 256, 0, stream>>>(dst, bcnt, E);
        k_pscan<<<1, 256, 0, stream>>>(bcnt, bbase, bcur);
        const int chunk = (E + PFB - 1) / PFB;
        if (chunk <= SBUF_CAP)
            k_pfill_sort<<<PFB, 256, 0, stream>>>(src, dst, bcur, pairs, E);
        else
            k_pfill<<<PFB, 256, 0, stream>>>(src, dst, bcur, pairs, E);
        k_agg_gemm<<<NBKT, 256, 0, stream>>>((const ushort4*)xb, pairs, bbase, bcnt,
                                             Wb, b, hb, stat);
        k_final<<<1, 256, 0, stream>>>(stat, bnw, bnb, stat + 512);
        k_norm8<<<(n8 + 255) / 256, 256, 0, stream>>>((const ushort8v*)hb, stat + 512,
                                                      (float4*)out, n8);
    } else if (ws_size >= need_mid) {
        hipMemsetAsync(fstat, 0, 2 * 256 * sizeof(float), stream);
        hipMemsetAsync(cnt, 0, NN * sizeof(int), stream);
        k_hist<<<(E + 255) / 256, 256, 0, stream>>>(dst, cnt, E);
        k_scan1<<<NBLK_SCAN, 256, 0, stream>>>(cnt, offs, bsum);
        k_scan2<<<1, 64, 0, stream>>>(bsum, NBLK_SCAN);
        k_scan3<<<(NN + 255) / 256, 256, 0, stream>>>(offs, bsum, cursor);
        k_bucket<<<(E + 255) / 256, 256, 0, stream>>>(src, dst, cursor, csr, E);
        k_gather<<<(NN + 3) / 4, 256, 0, stream>>>((const float4*)x, offs, cnt, csr,
                                                   (float4*)out);
        k_gemm_stats<<<(NN + RB - 1) / RB, 256, 0, stream>>>(out, W, b, fstat);
        k_final<<<1, 256, 0, stream>>>(fstat, bnw, bnb, fstat + 512);
        k_norm<<<(n4 + 255) / 256, 256, 0, stream>>>(out, fstat + 512, n4);
    } else {
        hipMemsetAsync(fstat, 0, 2 * 256 * sizeof(float), stream);
        k_copy<<<(n4 + 255) / 256, 256, 0, stream>>>((const float4*)x, (float4*)out, n4);
        long threads = (long)E * 64;
        k_scatter<<<(int)((threads + 255) / 256), 256, 0, stream>>>(x, src, dst, out, E);
        k_gemm_stats<<<(NN + RB - 1) / RB, 256, 0, stream>>>(out, W, b, fstat);
        k_final<<<1, 256, 0, stream>>>(fstat, bnw, bnb, fstat + 512);
        k_norm<<<(n4 + 255) / 256, 256, 0, stream>>>(out, fstat + 512, n4);
    }
}